// Round 1
// 4981.484 us; speedup vs baseline: 1.5771x; 1.5771x over previous
//
#include <hip/hip_runtime.h>
#include <hip/hip_bf16.h>

#define TLEN 512
#define NB   32
#define HID  768
#define NBLK 68
#define PERLINE 17   // NBLK/4 arrivals per counter line

typedef __attribute__((ext_vector_type(8))) short bf16x8;
typedef __attribute__((ext_vector_type(4))) float f32x4;
typedef unsigned short u16;
typedef unsigned int u32;
typedef unsigned long long u64;

__device__ __forceinline__ float bf2f(u16 u) {
  u32 t = ((u32)u) << 16; float f; __builtin_memcpy(&f, &t, 4); return f;
}
__device__ __forceinline__ u16 f2bf(float f) {
  u32 t; __builtin_memcpy(&t, &f, 4);
  u32 r = t + 0x7FFFu + ((t >> 16) & 1u);
  return (u16)(r >> 16);
}
// dual-dtype scalar loads: f!=0 -> input buffer is fp32, else packed bf16
__device__ __forceinline__ u16 ldbf(const void* p, size_t i, u32 f) {
  return f ? f2bf(((const float*)p)[i]) : ((const u16*)p)[i];
}
__device__ __forceinline__ float ldf(const void* p, size_t i, u32 f) {
  return f ? ((const float*)p)[i] : bf2f(((const u16*)p)[i]);
}
__device__ __forceinline__ float sigm(float x) { return 1.0f / (1.0f + __expf(-x)); }
__device__ __forceinline__ float tanh_(float x) { return 1.0f - 2.0f / (1.0f + __expf(2.0f * x)); }

// ---- agent-scope (cross-XCD coherent) accesses: bypass stale L2 ----
__device__ __forceinline__ u64 cld64(const u16* p) {
  return __hip_atomic_load((const u64*)p, __ATOMIC_RELAXED, __HIP_MEMORY_SCOPE_AGENT);
}
__device__ __forceinline__ void cst64(u16* p, u64 v) {
  __hip_atomic_store((u64*)p, v, __ATOMIC_RELAXED, __HIP_MEMORY_SCOPE_AGENT);
}
__device__ __forceinline__ bf16x8 cld128(const u16* p) {
  union { u64 q[2]; bf16x8 v; } u;
  u.q[0] = cld64(p); u.q[1] = cld64(p + 4);
  return u.v;
}
// wave-internal LDS fence (lockstep wave64: write->fence->read is safe)
__device__ __forceinline__ void wfence() {
  asm volatile("s_waitcnt lgkmcnt(0)" ::: "memory");
}

// ---------------- prologue: dtype sniff + h0/c0 conversion -------------------
__global__ __launch_bounds__(256) void prologue(const void* __restrict__ x,
                                                const void* __restrict__ h0,
                                                const void* __restrict__ c0,
                                                u32* __restrict__ flag,
                                                u16* __restrict__ h0b,
                                                float* __restrict__ c0f) {
  __shared__ u32 sflag;
  if (threadIdx.x == 0) {
    const u32* w = (const u32*)x;
    int cnt = 0;
    for (int m = 0; m < 256; ++m) {
      u32 e = ((w[m] & 0xFFFFu) >> 7) & 0xFFu;
      cnt += (e >= 100u && e <= 140u) ? 1 : 0;
    }
    sflag = (cnt >= 128) ? 0u : 1u;  // 1 = fp32 inputs
    flag[0] = sflag;
  }
  __syncthreads();
  const u32 f = sflag;
  for (int i = threadIdx.x; i < NB * HID; i += 256) {
    h0b[i] = ldbf(h0, i, f);
    c0f[i] = ldf(c0, i, f);
  }
}

// ---------------- transpose (R x C row-major -> C x R, emits bf16) ----------
__global__ __launch_bounds__(256) void transpose_any(const void* __restrict__ in,
                                                     u16* __restrict__ out, int R, int C,
                                                     const u32* __restrict__ flag) {
  const u32 f = flag[0];
  __shared__ u16 tile[64][65];
  int c0 = blockIdx.x * 64, r0 = blockIdx.y * 64;
  int tx = threadIdx.x & 63, ty = threadIdx.x >> 6;
#pragma unroll
  for (int j = 0; j < 16; ++j) {
    int r = ty + 4 * j;
    tile[r][tx] = ldbf(in, (size_t)(r0 + r) * C + c0 + tx, f);
  }
  __syncthreads();
#pragma unroll
  for (int j = 0; j < 16; ++j) {
    int r = ty + 4 * j;
    out[(size_t)(c0 + r) * R + r0 + tx] = tile[tx][r];
  }
}

// ---------------- QKV precompute: [16384 x 768] @ [768 x 2304] --------------
__global__ __launch_bounds__(256) void qkv_gemm(const void* __restrict__ X, const u16* __restrict__ WT,
                                                const void* __restrict__ bq, const void* __restrict__ bk,
                                                const void* __restrict__ bv,
                                                u16* __restrict__ Qx, u16* __restrict__ Kx,
                                                u16* __restrict__ Vx, const u32* __restrict__ flag) {
  const u32 f = flag[0];
  __shared__ __align__(16) u16 As[128][40];
  __shared__ __align__(16) u16 Bs[128][40];
  const int m0 = blockIdx.x * 128;
  const int n0 = blockIdx.y * 128;
  const int tid = threadIdx.x;
  const int lane = tid & 63, w = tid >> 6;
  const int l15 = lane & 15, l4 = lane >> 4;
  f32x4 zero4 = {0.f, 0.f, 0.f, 0.f};
  f32x4 acc[2][8];
#pragma unroll
  for (int h = 0; h < 2; ++h)
#pragma unroll
    for (int nt = 0; nt < 8; ++nt) acc[h][nt] = zero4;
  const int srow = tid >> 1, skp = (tid & 1) * 16;
  for (int k0 = 0; k0 < 768; k0 += 32) {
    __syncthreads();
    if (f) {
      const float* Xf = (const float*)X + (size_t)(m0 + srow) * 768 + k0 + skp;
#pragma unroll
      for (int q = 0; q < 16; ++q) As[srow][skp + q] = f2bf(Xf[q]);
    } else {
      const u16* Xh = (const u16*)X + (size_t)(m0 + srow) * 768 + k0 + skp;
      *(bf16x8*)&As[srow][skp]     = *(const bf16x8*)(Xh);
      *(bf16x8*)&As[srow][skp + 8] = *(const bf16x8*)(Xh + 8);
    }
    *(bf16x8*)&Bs[srow][skp]     = *(const bf16x8*)(WT + (size_t)(n0 + srow) * 768 + k0 + skp);
    *(bf16x8*)&Bs[srow][skp + 8] = *(const bf16x8*)(WT + (size_t)(n0 + srow) * 768 + k0 + skp + 8);
    __syncthreads();
    const int kl = 8 * l4;
    bf16x8 a0 = *(const bf16x8*)&As[32 * w + l15][kl];
    bf16x8 a1 = *(const bf16x8*)&As[32 * w + 16 + l15][kl];
#pragma unroll
    for (int nt = 0; nt < 8; ++nt) {
      bf16x8 b = *(const bf16x8*)&Bs[16 * nt + l15][kl];
      acc[0][nt] = __builtin_amdgcn_mfma_f32_16x16x32_bf16(a0, b, acc[0][nt], 0, 0, 0);
      acc[1][nt] = __builtin_amdgcn_mfma_f32_16x16x32_bf16(a1, b, acc[1][nt], 0, 0, 0);
    }
  }
#pragma unroll
  for (int h = 0; h < 2; ++h)
#pragma unroll
    for (int nt = 0; nt < 8; ++nt)
#pragma unroll
      for (int r = 0; r < 4; ++r) {
        const int m = m0 + 32 * w + 16 * h + 4 * l4 + r;
        const int n = n0 + 16 * nt + l15;
        float bias; u16* dst;
        if (n < 768)       { bias = ldf(bq, n, f);        dst = Qx + (size_t)m * 768 + n; }
        else if (n < 1536) { bias = ldf(bk, n - 768, f);  dst = Kx + (size_t)m * 768 + (n - 768); }
        else               { bias = ldf(bv, n - 1536, f); dst = Vx + (size_t)m * 768 + (n - 1536); }
        *dst = f2bf(acc[h][nt][r] + bias);
      }
}

// ---------------- persistent sequential scan ---------------------------------
// 68 blocks x 256 threads: bid<48 gates (4 waves, 16 cols each), bid<60 kv
// (4 waves, 32 cols each), bid<68 attn (4 waves, 1 batch each). Each gates/kv
// block stages the shared A-operand (rowbuf [+h]) into LDS once per step with
// batched agent-scope loads, then all waves run the MFMA loop from LDS.
struct ScanParams {
  const void *x, *bih, *bhh, *bk, *bv;
  const u16 *h0b;
  const float *c0f;
  const int* ping;
  const u16 *WihT, *WhhT, *WqkvT;
  const u16 *Qx;
  u16 *Kx, *Vx;
  u16 *rowbuf, *hsb;
  void* out;
  u32 *ctr;       // [0,32,64,96]=arrival lines, [320]=kvctr
  const u32* flag;
};

// drain all waves' stores, then one arrival per block
__device__ __forceinline__ void g_sync_arrive(u32* ctr, int bid) {
  __builtin_amdgcn_s_waitcnt(0);
  __syncthreads();
  if (threadIdx.x == 0)
    __hip_atomic_fetch_add(&ctr[(bid & 3) * 32], 1u, __ATOMIC_RELAXED, __HIP_MEMORY_SCOPE_AGENT);
}
// wave 0 polls the 4 lines directly; broadcasts to other waves via LDS flag
__device__ __forceinline__ void g_wait(u32* ctr, u32 z, u32* sep) {
  if (threadIdx.x < 64) {
    const u32 tgt = PERLINE * z;
    for (;;) {
      u32 mine = tgt;
      if (threadIdx.x < 4)
        mine = __hip_atomic_load(&ctr[threadIdx.x * 32], __ATOMIC_RELAXED, __HIP_MEMORY_SCOPE_AGENT);
      if (__all(mine >= tgt)) break;
      __builtin_amdgcn_s_sleep(1);
    }
    if (threadIdx.x == 0)
      __hip_atomic_store(sep, z, __ATOMIC_RELAXED, __HIP_MEMORY_SCOPE_WORKGROUP);
  } else {
    while (__hip_atomic_load(sep, __ATOMIC_RELAXED, __HIP_MEMORY_SCOPE_WORKGROUP) < z)
      __builtin_amdgcn_s_sleep(1);
  }
  asm volatile("" ::: "memory");
}

__global__ __launch_bounds__(256, 1) void scan_kernel(ScanParams P) {
  // LDS layout (union across roles):
  //  gates: As 0..98304 | gbuf 98304..106496 | htile 106496..107520
  //  kv:    As 0..49152 | tile 49152..57344
  //  attn:  sbuf 0..18432 | sping 18432..26624
  //  all:   sep @107520
  __shared__ __align__(16) unsigned char SH[107552];
  const int bid = blockIdx.x;
  const int tid = threadIdx.x;
  const int wid = tid >> 6;
  const int lane = tid & 63;
  const int l15 = lane & 15, l4 = lane >> 4;
  const u32 f = P.flag[0];
  u32* ctr = P.ctr;
  u32* sep = (u32*)(SH + 107520);
  if (tid == 0) *sep = 0;
  u32 z = 1;

  if (bid < 48) {
    // ------- gates: wave gw computes cols jb..jb+3 of each {i,f,g,o} block ----
    u16* As = (u16*)SH;                                  // [32][192 chunks][8]
    float* gbw = (float*)(SH + 98304) + wid * 512;       // [32][4][4]
    u16* htw = (u16*)(SH + 106496) + wid * 128;          // [32][4]
    const int gw = bid * 4 + wid;
    const int jb = 4 * gw;
    const int q_ = l15 >> 2, jl = l15 & 3;
    const int colW = 768 * q_ + jb + jl;
    bf16x8 Bfr[48];
#pragma unroll
    for (int s = 0; s < 48; ++s) {
      int k = 32 * s + 8 * l4;
      const u16* src = (s < 24) ? (P.WihT + (size_t)colW * HID + k)
                                : (P.WhhT + (size_t)colW * HID + (k - 768));
      Bfr[s] = *(const bf16x8*)src;
    }
    const float biasv = ldf(P.bih, colW, f) + ldf(P.bhh, colW, f);
    const int cb = lane >> 1, cj = 2 * (lane & 1);
    float cst0 = P.c0f[(size_t)cb * HID + jb + cj];
    float cst1 = P.c0f[(size_t)cb * HID + jb + cj + 1];
    g_sync_arrive(ctr, bid); g_wait(ctr, z, sep); ++z;   // prologue: row_0 ready

    for (int i = 0; i < TLEN; ++i) {
      const u16* rowp = P.rowbuf + (size_t)(i & 1) * NB * HID;
      const u16* hp = (i == 0) ? P.h0b : (P.hsb + (size_t)((i - 1) & 1) * NB * HID);
      // ---- stage A = [row | h] (32 x 1536 bf16) into LDS, swizzled chunks ----
      bf16x8 stg[24];
#pragma unroll
      for (int j = 0; j < 24; ++j) {
        int g = tid + 256 * j;
        int r = g / 192, c = g - r * 192;
        const u16* src = (c < 96) ? (rowp + (size_t)r * HID + c * 8)
                                  : (hp + (size_t)r * HID + (c - 96) * 8);
        stg[j] = cld128(src);
      }
#pragma unroll
      for (int j = 0; j < 24; ++j) {
        int g = tid + 256 * j;
        int r = g / 192, c = g - r * 192;
        *(bf16x8*)&As[(r * 192 + (c ^ (r & 7))) * 8] = stg[j];
      }
      __syncthreads();
      // ---- MFMA loop from LDS ----
      f32x4 acc0 = {0.f, 0.f, 0.f, 0.f}, acc1 = {0.f, 0.f, 0.f, 0.f};
#pragma unroll
      for (int s = 0; s < 48; ++s) {
        int cc = (4 * s + l4) ^ (l15 & 7);
        bf16x8 a0 = *(const bf16x8*)&As[(l15 * 192 + cc) * 8];
        bf16x8 a1 = *(const bf16x8*)&As[((l15 + 16) * 192 + cc) * 8];
        acc0 = __builtin_amdgcn_mfma_f32_16x16x32_bf16(a0, Bfr[s], acc0, 0, 0, 0);
        acc1 = __builtin_amdgcn_mfma_f32_16x16x32_bf16(a1, Bfr[s], acc1, 0, 0, 0);
      }
#pragma unroll
      for (int r = 0; r < 4; ++r) {
        gbw[(4 * l4 + r) * 16 + q_ * 4 + jl] = acc0[r] + biasv;
        gbw[(16 + 4 * l4 + r) * 16 + q_ * 4 + jl] = acc1[r] + biasv;
      }
      wfence();
      float ig0 = gbw[cb * 16 + cj],      fg0 = gbw[cb * 16 + 4 + cj];
      float gg0 = gbw[cb * 16 + 8 + cj],  og0 = gbw[cb * 16 + 12 + cj];
      float ig1 = gbw[cb * 16 + cj + 1],  fg1 = gbw[cb * 16 + 4 + cj + 1];
      float gg1 = gbw[cb * 16 + 8 + cj + 1], og1 = gbw[cb * 16 + 12 + cj + 1];
      cst0 = sigm(fg0) * cst0 + sigm(ig0) * tanh_(gg0);
      cst1 = sigm(fg1) * cst1 + sigm(ig1) * tanh_(gg1);
      float h0v = sigm(og0) * tanh_(cst0);
      float h1v = sigm(og1) * tanh_(cst1);
      htw[cb * 4 + cj] = f2bf(h0v); htw[cb * 4 + cj + 1] = f2bf(h1v);
      wfence();
      if (lane < 32) {
        u64 hv; __builtin_memcpy(&hv, &htw[lane * 4], 8);
        cst64(P.hsb + (size_t)(i & 1) * NB * HID + (size_t)lane * HID + jb, hv);
      }
      g_sync_arrive(ctr, bid);
      // out stores off the critical path (acked before next step's drain)
      const size_t o1 = (size_t)i * NB * HID + (size_t)cb * HID + jb + cj;
      if (f) { float* O = (float*)P.out; O[o1] = h0v; O[o1 + 1] = h1v; }
      else   { u16*   O = (u16*)P.out;   O[o1] = f2bf(h0v); O[o1 + 1] = f2bf(h1v); }
      if (i == TLEN - 1) {
        const size_t oh = (size_t)TLEN * NB * HID + (size_t)cb * HID + jb + cj;
        const size_t oc = (size_t)(TLEN + 1) * NB * HID + (size_t)cb * HID + jb + cj;
        if (f) { float* O = (float*)P.out; O[oh] = h0v; O[oh + 1] = h1v; O[oc] = cst0; O[oc + 1] = cst1; }
        else   { u16*   O = (u16*)P.out;   O[oh] = f2bf(h0v); O[oh + 1] = f2bf(h1v);
                 O[oc] = f2bf(cst0); O[oc + 1] = f2bf(cst1); }
      }
      g_wait(ctr, z, sep); ++z;
    }
  } else if (bid < 60) {
    // ------- k/v projection: wave kw computes 32 cols of K or V ---------------
    u16* As = (u16*)SH;                                  // [32][96 chunks][8]
    u16* tile = (u16*)(SH + 49152) + wid * 1024;         // [32][32]
    const int kw = (bid - 48) * 4 + wid;
    const int col0 = 32 * kw;
    const bool isV = (col0 >= 768);
    const u16* Wt = P.WqkvT + (size_t)(768 + col0) * HID;
    const int oc0 = isV ? (col0 - 768) : col0;
    u16* obase = isV ? P.Vx : P.Kx;
    const void* bias_src = isV ? P.bv : P.bk;
    const float bias0 = ldf(bias_src, oc0 + l15, f);
    const float bias1 = ldf(bias_src, oc0 + 16 + l15, f);
    bf16x8 Bfr[48];
#pragma unroll
    for (int s = 0; s < 24; ++s) {
      int k = 32 * s + 8 * l4;
      Bfr[2 * s]     = *(const bf16x8*)(Wt + (size_t)l15 * HID + k);
      Bfr[2 * s + 1] = *(const bf16x8*)(Wt + (size_t)(16 + l15) * HID + k);
    }
    g_sync_arrive(ctr, bid); g_wait(ctr, z, sep); ++z;   // prologue

    for (int i = 0; i < TLEN; ++i) {
      const u16* rowp = P.rowbuf + (size_t)(i & 1) * NB * HID;
      // ---- stage row (32 x 768 bf16) into LDS ----
      bf16x8 stg[12];
#pragma unroll
      for (int j = 0; j < 12; ++j) {
        int g = tid + 256 * j;
        int r = g / 96, c = g - r * 96;
        stg[j] = cld128(rowp + (size_t)r * HID + c * 8);
      }
#pragma unroll
      for (int j = 0; j < 12; ++j) {
        int g = tid + 256 * j;
        int r = g / 96, c = g - r * 96;
        *(bf16x8*)&As[(r * 96 + (c ^ (r & 7))) * 8] = stg[j];
      }
      __syncthreads();
      f32x4 a00 = {0.f,0.f,0.f,0.f}, a01 = {0.f,0.f,0.f,0.f};
      f32x4 a10 = {0.f,0.f,0.f,0.f}, a11 = {0.f,0.f,0.f,0.f};
#pragma unroll
      for (int s = 0; s < 24; ++s) {
        int cc = (4 * s + l4) ^ (l15 & 7);
        bf16x8 r0 = *(const bf16x8*)&As[(l15 * 96 + cc) * 8];
        bf16x8 r1 = *(const bf16x8*)&As[((l15 + 16) * 96 + cc) * 8];
        a00 = __builtin_amdgcn_mfma_f32_16x16x32_bf16(r0, Bfr[2 * s],     a00, 0, 0, 0);
        a01 = __builtin_amdgcn_mfma_f32_16x16x32_bf16(r0, Bfr[2 * s + 1], a01, 0, 0, 0);
        a10 = __builtin_amdgcn_mfma_f32_16x16x32_bf16(r1, Bfr[2 * s],     a10, 0, 0, 0);
        a11 = __builtin_amdgcn_mfma_f32_16x16x32_bf16(r1, Bfr[2 * s + 1], a11, 0, 0, 0);
      }
#pragma unroll
      for (int r = 0; r < 4; ++r) {
        int b0 = 4 * l4 + r;
        tile[b0 * 32 + l15]             = f2bf(a00[r] + bias0);
        tile[b0 * 32 + 16 + l15]        = f2bf(a01[r] + bias1);
        tile[(16 + b0) * 32 + l15]      = f2bf(a10[r] + bias0);
        tile[(16 + b0) * 32 + 16 + l15] = f2bf(a11[r] + bias1);
      }
      wfence();
      {
        u16* ob = obase + (size_t)i * NB * HID + oc0;
        const int row = lane >> 1, ch = (lane & 1) * 16;
#pragma unroll
        for (int q = 0; q < 4; ++q) {
          u64 w8; __builtin_memcpy(&w8, &tile[row * 32 + ch + 4 * q], 8);
          cst64(ob + (size_t)row * HID + ch + 4 * q, w8);
        }
      }
      // drain, publish kv-row-complete, arrive
      __builtin_amdgcn_s_waitcnt(0);
      __syncthreads();
      if (tid == 0) {
        __hip_atomic_fetch_add(&ctr[320], 1u, __ATOMIC_RELAXED, __HIP_MEMORY_SCOPE_AGENT);
        __hip_atomic_fetch_add(&ctr[(bid & 3) * 32], 1u, __ATOMIC_RELAXED, __HIP_MEMORY_SCOPE_AGENT);
      }
      g_wait(ctr, z, sep); ++z;
    }
  } else {
    // ------- attention: wave = one batch; computes row_{i+1} in interval i ----
    const int b = (bid - 60) * 4 + wid;
    u16* sb = (u16*)SH + wid * 2304;                     // [3][768]
    int* spng = (int*)(SH + 18432) + wid * 512;
    for (int j = lane; j < TLEN; j += 64) spng[j] = P.ping[(size_t)b * TLEN + j];
    {  // prologue: row_0 = x[0] (t=0 mask false)
      const size_t xoff = (size_t)b * HID + 12 * lane;
      u16* orow = P.rowbuf + (size_t)b * HID + 12 * lane;
#pragma unroll
      for (int q = 0; q < 3; ++q) {
        u16 e[4];
#pragma unroll
        for (int t2 = 0; t2 < 4; ++t2) e[t2] = ldbf(P.x, xoff + 4 * q + t2, f);
        u64 w8; __builtin_memcpy(&w8, e, 8);
        cst64(orow + 4 * q, w8);
      }
    }
    g_sync_arrive(ctr, bid); g_wait(ctr, z, sep); ++z;   // prologue

    for (int i = 0; i < TLEN; ++i) {
      if (i < TLEN - 1) {
        const int t = i + 1;
        const int p = spng[t];
        u16* orow = P.rowbuf + (size_t)(t & 1) * NB * HID + (size_t)b * HID;
        if (p == 0) {  // mask false -> row = x[t]
          const size_t xoff = ((size_t)t * NB + b) * HID + 12 * lane;
#pragma unroll
          for (int q = 0; q < 3; ++q) {
            u16 e[4];
#pragma unroll
            for (int t2 = 0; t2 < 4; ++t2) e[t2] = ldbf(P.x, xoff + 4 * q + t2, f);
            u64 w8; __builtin_memcpy(&w8, e, 8);
            cst64(orow + 12 * lane + 4 * q, w8);
          }
        } else {
          const int idx = p - 1;
          // q / right-key / right-value: static rows, plain loads, issued early
          const u16* qp = P.Qx + ((size_t)t * NB + b) * HID;  // never rewritten
          const u16* kR = P.Kx + ((size_t)t * NB + b) * HID;  // untouched until interval t
          const u16* vR = P.Vx + ((size_t)t * NB + b) * HID;
          float qv[12], krv[12], vrv[12];
#pragma unroll
          for (int j = 0; j < 12; ++j) {
            qv[j]  = bf2f(qp[64 * j + lane]);
            krv[j] = bf2f(kR[64 * j + lane]);
            vrv[j] = bf2f(vR[64 * j + lane]);
          }
          if (idx == i) {  // produced this interval: wait for the 12 kv blocks
            while (__hip_atomic_load(&ctr[320], __ATOMIC_RELAXED, __HIP_MEMORY_SCOPE_AGENT) <
                   12u * (u32)(i + 1)) {
              __builtin_amdgcn_s_sleep(2);
            }
            asm volatile("" ::: "memory");
          }
          const u16* kL = P.Kx + ((size_t)idx * NB + b) * HID;
          const u16* vL = P.Vx + ((size_t)idx * NB + b) * HID;
#pragma unroll
          for (int q = 0; q < 3; ++q) {
            *(u64*)&sb[12 * lane + 4 * q]       = cld64(kL + 12 * lane + 4 * q);
            *(u64*)&sb[768 + 12 * lane + 4 * q] = cld64(vL + 12 * lane + 4 * q);
          }
          wfence();
          float d0[12], d1[12];
#pragma unroll
          for (int j = 0; j < 12; ++j) {
            d0[j] = qv[j] * bf2f(sb[64 * j + lane]);
            d1[j] = qv[j] * krv[j];
          }
#pragma unroll
          for (int m = 32; m > 0; m >>= 1) {
#pragma unroll
            for (int j = 0; j < 12; ++j) {
              d0[j] += __shfl_xor(d0[j], m);
              d1[j] += __shfl_xor(d1[j], m);
            }
          }
#pragma unroll
          for (int j = 0; j < 12; ++j) {
            float pw0 = sigm((d0[j] - d1[j]) * 0.125f);  // softmax over 2 keys
            float ov = pw0 * bf2f(sb[768 + 64 * j + lane]) + (1.0f - pw0) * vrv[j];
            sb[1536 + 64 * j + lane] = f2bf(ov);
          }
          wfence();
#pragma unroll
          for (int q = 0; q < 3; ++q) {
            u64 w8; __builtin_memcpy(&w8, &sb[1536 + 12 * lane + 4 * q], 8);
            cst64(orow + 12 * lane + 4 * q, w8);
          }
        }
      }
      g_sync_arrive(ctr, bid); g_wait(ctr, z, sep); ++z;
    }
  }
}

extern "C" void kernel_launch(void* const* d_in, const int* in_sizes, int n_in,
                              void* d_out, int out_size, void* d_ws, size_t ws_size,
                              hipStream_t stream) {
  const void* x   = d_in[0];
  const int* ping = (const int*)d_in[1];
  const void* h0  = d_in[2];
  const void* c0  = d_in[3];
  const void* wih = d_in[4];
  const void* whh = d_in[5];
  const void* bih = d_in[6];
  const void* bhh = d_in[7];
  const void* wq  = d_in[8];
  const void* bq  = d_in[9];
  const void* wk  = d_in[10];
  const void* bk  = d_in[11];
  const void* wv  = d_in[12];
  const void* bv  = d_in[13];
  (void)in_sizes; (void)n_in; (void)out_size; (void)ws_size;  // needs ~90 MB ws

  char* ws = (char*)d_ws;
  size_t off = 0;
  auto walloc = [&](size_t b) { char* p = ws + off; off += (b + 255) & ~(size_t)255; return p; };
  u32* ctr    = (u32*)walloc(2048);
  u32* flag   = ctr + 400;  // clear of lines 0..96, kvctr 320
  u16* WqkvT  = (u16*)walloc((size_t)2304 * 768 * 2);
  u16* WihT   = (u16*)walloc((size_t)3072 * 768 * 2);
  u16* WhhT   = (u16*)walloc((size_t)3072 * 768 * 2);
  u16* Qx     = (u16*)walloc((size_t)TLEN * NB * HID * 2);
  u16* Kx     = (u16*)walloc((size_t)TLEN * NB * HID * 2);
  u16* Vx     = (u16*)walloc((size_t)TLEN * NB * HID * 2);
  u16* rowbuf = (u16*)walloc((size_t)2 * NB * HID * 2);
  u16* h0b    = (u16*)walloc((size_t)NB * HID * 2);
  float* c0f  = (float*)walloc((size_t)NB * HID * 4);
  u16* hsb    = (u16*)walloc((size_t)2 * NB * HID * 2);

  hipMemsetAsync(ctr, 0, 2048, stream);
  prologue<<<1, 256, 0, stream>>>(x, h0, c0, flag, h0b, c0f);
  transpose_any<<<dim3(12, 12), 256, 0, stream>>>(wq, WqkvT, 768, 768, flag);
  transpose_any<<<dim3(12, 12), 256, 0, stream>>>(wk, WqkvT + (size_t)768 * 768, 768, 768, flag);
  transpose_any<<<dim3(12, 12), 256, 0, stream>>>(wv, WqkvT + (size_t)1536 * 768, 768, 768, flag);
  transpose_any<<<dim3(48, 12), 256, 0, stream>>>(wih, WihT, 768, 3072, flag);
  transpose_any<<<dim3(48, 12), 256, 0, stream>>>(whh, WhhT, 768, 3072, flag);
  qkv_gemm<<<dim3(128, 18), 256, 0, stream>>>(x, WqkvT, bq, bk, bv, Qx, Kx, Vx, flag);

  ScanParams P;
  P.x = x; P.bih = bih; P.bhh = bhh; P.bk = bk; P.bv = bv;
  P.h0b = h0b; P.c0f = c0f;
  P.ping = ping;
  P.WihT = WihT; P.WhhT = WhhT; P.WqkvT = WqkvT;
  P.Qx = Qx; P.Kx = Kx; P.Vx = Vx;
  P.rowbuf = rowbuf; P.hsb = hsb;
  P.out = d_out;
  P.ctr = ctr; P.flag = flag;
  scan_kernel<<<dim3(NBLK), dim3(256), 0, stream>>>(P);
}